// Round 5
// baseline (526.017 us; speedup 1.0000x reference)
//
#include <hip/hip_runtime.h>
#include <hip/hip_bf16.h>
#include <stdint.h>
#include <stddef.h>

// LiteratiQuantLinear: out = x @ (sign(w)*clamp(scales,1e-8))^T
// M=8192 (4x2048), N=4096 (O), K=4096 (C), group=128 along K.
//
// R7: R6 measured step time = MFMA(516) + LDS(576) summed: 8 barrier-synced
// waves get round-robin LDS service -> no wave stagger -> CU-shared LDS pipe
// and per-SIMD MFMA pipes alternate. Intra-wave pipelining can't fix this
// (register cliff at 252/256). Fix = TWO INDEPENDENT BLOCKS PER CU (m114
// co-schedule: no cross-block barriers -> block A's MFMA overlaps block B's
// LDS phase):
//   - BM x BN = 256x128, 4 waves (wave tile 128x64 unchanged, 32x32x16 MFMA,
//     acc = 128 AGPR; ~100 VGPR + 128 < 256 -> 2 waves/SIMD -> 2 blocks/CU)
//   - LDS ring-3 x 24 KiB = 72 KiB/block (144 KiB/CU)
//   - 6 DMA/wave/tile, stage t+2 during t, steady vmcnt(6) (ledger audited
//     below), tail vmcnt(0)/vmcnt(0)
//   - verified swizzle: slot(r,kc)=r*4+(kc^((r>>1)&3)), linear DMA dest,
//     pre-swizzled global source (SQ_LDS_BANK_CONFLICT==0 in R3/R4)
//   - XCD-bijective grid swizzle (1024 blocks, 1024%8==0)
// PREP: rewritten lane-coalesced (old: 16 elts/thread blocked -> lanes 64B
// apart, uncoalesced; non-gemm residual ~240us vs ~50us BW floor). Now 4
// block-strided float4/thread, lane-consecutive 16B loads + 8B stores.

#define M_DIM 8192
#define N_DIM 4096
#define K_DIM 4096
#define BM 256
#define BN 128
#define BK 32
#define NT (K_DIM / BK)  // 128 K-tiles

typedef __bf16 bf16x8 __attribute__((ext_vector_type(8)));
typedef __bf16 bf16x4 __attribute__((ext_vector_type(4)));
typedef float f32x16 __attribute__((ext_vector_type(16)));

__device__ __forceinline__ void async_copy16(const void* g, void* l) {
  __builtin_amdgcn_global_load_lds((__attribute__((address_space(1))) void*)g,
                                   (__attribute__((address_space(3))) void*)l,
                                   16, 0, 0);
}

// ---- prep: coalesced. float4 #i -> bf16x4 #i. X region: 8M float4s, W: 4M.
// Thread processes 4 float4s strided by blockDim (lanes consecutive 16B).
// Region boundary at float4 index 8M = block 8192 exactly -> uniform branch.
#define XF4 ((size_t)M_DIM * K_DIM / 4)  // 8M float4s
#define WF4 ((size_t)N_DIM * K_DIM / 4)  // 4M float4s
__global__ __launch_bounds__(256) void prep_kernel(
    const float4* __restrict__ x4, const float4* __restrict__ w4,
    const float* __restrict__ scales, bf16x4* __restrict__ xb4,
    bf16x4* __restrict__ wb4) {
  const size_t base = (size_t)blockIdx.x * 1024 + threadIdx.x;
  if (blockIdx.x < 8192) {  // X region (8192 blocks * 1024 = 8M float4s)
#pragma unroll
    for (int h = 0; h < 4; ++h) {
      const size_t i = base + h * 256;
      const float4 v = x4[i];
      bf16x4 o;
      o[0] = (__bf16)v.x; o[1] = (__bf16)v.y;
      o[2] = (__bf16)v.z; o[3] = (__bf16)v.w;
      xb4[i] = o;
    }
  } else {  // W region
#pragma unroll
    for (int h = 0; h < 4; ++h) {
      const size_t j = base + h * 256 - XF4;  // float4 index within w
      const size_t idx = j * 4;               // element index
      const int o_ = (int)(idx >> 12);        // / 4096
      const int grp = (int)(idx >> 7) & 31;   // group of 128
      const float s = fmaxf(scales[(o_ << 5) + grp], 1e-8f);
      const float4 v = w4[j];
      bf16x4 q;
      q[0] = (__bf16)((v.x >= 0.f) ? s : -s);
      q[1] = (__bf16)((v.y >= 0.f) ? s : -s);
      q[2] = (__bf16)((v.z >= 0.f) ? s : -s);
      q[3] = (__bf16)((v.w >= 0.f) ? s : -s);
      wb4[j] = q;
    }
  }
}

// ---- GEMM ----
// LDS per buffer: A 256x32 (16 KiB) + B 128x32 (8 KiB) = 24 KiB, ring of 3.
// Slot layout (slot = 16 B = 8 bf16 of k-chunk kc in 0..3):
//   slot(r, kc) = r*4 + (kc ^ ((r>>1)&3))   (bank-conflict-free, R3/R4)
// Staging call (one 16-row slab): lane l -> row l>>2, pre-swizzled global
// k-chunk kc = (l&3)^((l>>3)&3); LDS dest linear (uniform base + lane*16).
// Per wave per tile: A slabs {4w..4w+3} (4 calls) + B slabs {2w,2w+1} (2).
//
// vmcnt ledger (6 DMA/wave/tile): prologue stages tiles 0,1 (12), vmcnt(6)
// -> tile0 done, 6 outstanding (tile1). Tile t: stage t+2 (+6 -> 12),
// vmcnt(6) at end -> tile t+1 done, 6 left (t+2). Tail: end of 125 staged
// 127 -> vmcnt(6) (126 ready); tile 126 no stage, vmcnt(0) (127 ready);
// tile 127 no stage, vmcnt(0) no-op.
// WAR: DMA(t+2) targets buf[(t+2)%3] = buffer read during tile t-1; those
// reads were lgkm-consumed before tile t-1's end barrier, and the DMA issues
// after all waves passed it. Safe.

#define LDS_A(b) ((char*)lds + (b) * 24576)
#define LDS_B(b) ((char*)lds + (b) * 24576 + 16384)

#define STAGE_TO(b) do {                          \
    char* _dA = LDS_A(b);                         \
    char* _dB = LDS_B(b);                         \
    async_copy16(aP0, _dA + dA0);                 \
    async_copy16(aP1, _dA + dA1);                 \
    async_copy16(aP2, _dA + dA2);                 \
    async_copy16(aP3, _dA + dA3);                 \
    async_copy16(bP0, _dB + dB0);                 \
    async_copy16(bP1, _dB + dB1);                 \
  } while (0)

#define ADVANCE do {                              \
    aP0 += BK; aP1 += BK; aP2 += BK; aP3 += BK;   \
    bP0 += BK; bP1 += BK;                         \
  } while (0)

// BUF is compile-time 0..2. Stage target = (BUF+2)%3.
#define TILE_BODY(BUF, DO_STAGE, VMSTR) do {                                   \
    char* _bA = LDS_A(BUF);                                                    \
    char* _bB = LDS_B(BUF);                                                    \
    bf16x8 _av[4][2], _bv[2][2];                                               \
    /* ks0 frags first (first cluster's operands), then ks1 */                 \
    _Pragma("unroll") for (int _i = 0; _i < 4; ++_i)                           \
      _av[_i][0] = *(const bf16x8*)(_bA + aOff[_i][0]);                        \
    _Pragma("unroll") for (int _j = 0; _j < 2; ++_j)                           \
      _bv[_j][0] = *(const bf16x8*)(_bB + bOff[_j][0]);                        \
    _Pragma("unroll") for (int _i = 0; _i < 4; ++_i)                           \
      _av[_i][1] = *(const bf16x8*)(_bA + aOff[_i][1]);                        \
    _Pragma("unroll") for (int _j = 0; _j < 2; ++_j)                           \
      _bv[_j][1] = *(const bf16x8*)(_bB + bOff[_j][1]);                        \
    if (DO_STAGE) { STAGE_TO((BUF + 2) % 3); ADVANCE; }                        \
    __builtin_amdgcn_s_setprio(1);                                             \
    _Pragma("unroll") for (int _i = 0; _i < 4; ++_i)                           \
      _Pragma("unroll") for (int _j = 0; _j < 2; ++_j)                         \
        acc[_i][_j] = __builtin_amdgcn_mfma_f32_32x32x16_bf16(                 \
            _av[_i][0], _bv[_j][0], acc[_i][_j], 0, 0, 0);                     \
    _Pragma("unroll") for (int _i = 0; _i < 4; ++_i)                           \
      _Pragma("unroll") for (int _j = 0; _j < 2; ++_j)                         \
        acc[_i][_j] = __builtin_amdgcn_mfma_f32_32x32x16_bf16(                 \
            _av[_i][1], _bv[_j][1], acc[_i][_j], 0, 0, 0);                     \
    __builtin_amdgcn_s_setprio(0);                                             \
    asm volatile("s_waitcnt " VMSTR ::: "memory");                             \
    __builtin_amdgcn_s_barrier();                                              \
    __builtin_amdgcn_sched_barrier(0); /* tile boundary fence */               \
  } while (0)

__global__ __launch_bounds__(256, 2) void literati_gemm(
    const __bf16* __restrict__ Ab, const __bf16* __restrict__ Bb,
    float* __restrict__ C) {
  __shared__ __align__(16) char lds[3 * 24576];  // 72 KiB ring-3

  const int tid = threadIdx.x;
  const int lane = tid & 63;
  const int wave = tid >> 6;       // 0..3
  // XCD-bijective swizzle of the linear block id (1024 blocks, %8==0)
  const int lin = blockIdx.y * 32 + blockIdx.x;
  const int swz = (lin & 7) * 128 + (lin >> 3);
  const int bn0 = (swz & 31) * BN;   // 32 N-blocks
  const int bm0 = (swz >> 5) * BM;   // 32 M-blocks
  const int wm = wave >> 1;        // 0..1: 128-row half
  const int wn = wave & 1;         // 0..1: 64-col half

  // ---- staging decomposition ----
  const int r_in = lane >> 2;                        // 0..15 row within slab
  const int kc_st = (lane & 3) ^ ((lane >> 3) & 3);  // pre-swizzled k-chunk
  const int sA = wave * 4;   // A slabs sA..sA+3 (of 16)
  const int sB = wave * 2;   // B slabs sB..sB+1 (of 8)
  const __bf16* aP0 = Ab + (size_t)(bm0 + (sA + 0) * 16 + r_in) * K_DIM + kc_st * 8;
  const __bf16* aP1 = Ab + (size_t)(bm0 + (sA + 1) * 16 + r_in) * K_DIM + kc_st * 8;
  const __bf16* aP2 = Ab + (size_t)(bm0 + (sA + 2) * 16 + r_in) * K_DIM + kc_st * 8;
  const __bf16* aP3 = Ab + (size_t)(bm0 + (sA + 3) * 16 + r_in) * K_DIM + kc_st * 8;
  const __bf16* bP0 = Bb + (size_t)(bn0 + (sB + 0) * 16 + r_in) * K_DIM + kc_st * 8;
  const __bf16* bP1 = Bb + (size_t)(bn0 + (sB + 1) * 16 + r_in) * K_DIM + kc_st * 8;
  const int dA0 = ((sA + 0) * 64 + lane) * 16;
  const int dA1 = ((sA + 1) * 64 + lane) * 16;
  const int dA2 = ((sA + 2) * 64 + lane) * 16;
  const int dA3 = ((sA + 3) * 64 + lane) * 16;
  const int dB0 = ((sB + 0) * 64 + lane) * 16;
  const int dB1 = ((sB + 1) * 64 + lane) * 16;

  // ---- fragment LDS byte offsets (32x32x16, R2/R6-verified) ----
  const int m32 = lane & 31;
  const int hl = lane >> 5;  // 0/1
  int aOff[4][2], bOff[2][2];
#pragma unroll
  for (int i = 0; i < 4; ++i) {
    const int row = wm * 128 + i * 32 + m32;   // 0..255
#pragma unroll
    for (int ks = 0; ks < 2; ++ks) {
      const int kc = 2 * ks + hl;
      aOff[i][ks] = (row * 4 + (kc ^ ((row >> 1) & 3))) * 16;
    }
  }
#pragma unroll
  for (int j = 0; j < 2; ++j) {
    const int row = wn * 64 + j * 32 + m32;    // 0..127
#pragma unroll
    for (int ks = 0; ks < 2; ++ks) {
      const int kc = 2 * ks + hl;
      bOff[j][ks] = (row * 4 + (kc ^ ((row >> 1) & 3))) * 16;
    }
  }

  f32x16 acc[4][2];
#pragma unroll
  for (int i = 0; i < 4; ++i)
#pragma unroll
    for (int j = 0; j < 2; ++j)
#pragma unroll
      for (int r = 0; r < 16; ++r) acc[i][j][r] = 0.f;

  // ---- prologue: stage tiles 0,1 (12 DMA), wait tile 0 ----
  STAGE_TO(0); ADVANCE;
  STAGE_TO(1); ADVANCE;
  asm volatile("s_waitcnt vmcnt(6)" ::: "memory");
  __builtin_amdgcn_s_barrier();
  __builtin_amdgcn_sched_barrier(0);

  // ---- main loop: tiles 0..125 (42 x unroll-3), ring index compile-time ----
  for (int tq = 0; tq < 42; ++tq) {
    TILE_BODY(0, 1, "vmcnt(6)");
    TILE_BODY(1, 1, "vmcnt(6)");
    TILE_BODY(2, 1, "vmcnt(6)");
  }
  // tiles 126 (buf 0), 127 (buf 1): no staging, drain
  TILE_BODY(0, 0, "vmcnt(0)");
  TILE_BODY(1, 0, "vmcnt(0)");

  // ---- epilogue: col = lane&31, row = (r&3)+8*(r>>2)+4*hl (verified) ----
#pragma unroll
  for (int i = 0; i < 4; ++i) {
#pragma unroll
    for (int j = 0; j < 2; ++j) {
      const int col = bn0 + wn * 64 + j * 32 + m32;
      const int rbase = bm0 + wm * 128 + i * 32 + 4 * hl;
#pragma unroll
      for (int r = 0; r < 16; ++r) {
        const int row = rbase + (r & 3) + 8 * (r >> 2);
        C[(size_t)row * N_DIM + col] = acc[i][j][r];
      }
    }
  }
}

extern "C" void kernel_launch(void* const* d_in, const int* in_sizes, int n_in,
                              void* d_out, int out_size, void* d_ws, size_t ws_size,
                              hipStream_t stream) {
  (void)in_sizes; (void)n_in; (void)out_size; (void)ws_size;
  const float* x = (const float*)d_in[0];      // (4,2048,4096) fp32
  const float* w = (const float*)d_in[1];      // (4096,4096) fp32
  const float* sc = (const float*)d_in[2];     // (4096,32) fp32
  float* out = (float*)d_out;                  // (4,2048,4096) fp32

  __bf16* xb = (__bf16*)d_ws;
  __bf16* wb = xb + (size_t)M_DIM * K_DIM;

  // prep: (8M + 4M) float4s, 1024 per block -> 12288 blocks
  prep_kernel<<<12288, 256, 0, stream>>>((const float4*)x, (const float4*)w,
                                         sc, (bf16x4*)xb, (bf16x4*)wb);

  dim3 grid(N_DIM / BN, M_DIM / BM);  // (32, 32) = 1024 blocks
  literati_gemm<<<grid, 256, 0, stream>>>(xb, wb, out);
}